// Round 4
// baseline (177.854 us; speedup 1.0000x reference)
//
#include <hip/hip_runtime.h>
#include <cstdint>

#define IDF 256
#define CDF 256
#define NL  128
#define HXW 4096
#define NB  32
#define PTILE 64

typedef _Float16 f16x8 __attribute__((ext_vector_type(8)));
typedef __fp16 fp16x2 __attribute__((ext_vector_type(2)));
typedef float f32x4 __attribute__((ext_vector_type(4)));
typedef unsigned short u16;
typedef unsigned int u32;

union Frag { f16x8 v; u32 u[4]; uint2 u2[2]; uint4 u4; };

__device__ __forceinline__ u16 f2h(float f) { union { _Float16 h; u16 s; } c; c.h = (_Float16)f; return c.s; }
__device__ __forceinline__ u32 pkrtz(float a, float b) {
  union { fp16x2 v; u32 u; } c;
  c.v = __builtin_amdgcn_cvt_pkrtz(a, b);
  return c.u;
}

// ws layout (bytes): [0..3] mode flag; [256..767] packed mask bits (32 rows x 4 u32);
// [1024 ..] srcF f16 [b][i][l] (2 MB); [+2MB ..] srcT f16 [b][l][i] (2 MB).

// ---------------- prep: mask dtype detection + bit packing ----------------
__global__ void prep_kernel(const u32* __restrict__ m, u32* __restrict__ ws0) {
  __shared__ int bi_s, bf_s, mode_s;
  if (threadIdx.x == 0) { bi_s = 0; bf_s = 0; }
  __syncthreads();
  int bi = 0, bfl = 0;
  for (int k = 0; k < 4; ++k) {
    u32 v = m[threadIdx.x * 4 + k];   // first 4KB: valid subset for i32/f32/u8
    if (v > 1u) bi = 1;               // int32 0/1 never exceeds 1
    float f = __uint_as_float(v);
    if (!(f == 0.0f || f == 1.0f)) bfl = 1;
  }
  if (bi) atomicOr(&bi_s, 1);
  if (bfl) atomicOr(&bf_s, 1);
  __syncthreads();
  if (threadIdx.x == 0) { mode_s = (bi_s == 0) ? 0 : ((bf_s == 0) ? 1 : 2); ws0[0] = (u32)mode_s; }
  __syncthreads();
  const int mode = mode_s;
  if (threadIdx.x < 128) {
    int row = threadIdx.x >> 2, q = threadIdx.x & 3;
    u32 bits = 0;
    for (int c = 0; c < 32; ++c) {
      int idx = row * NL + q * 32 + c;
      int mv;
      if (mode == 0)      mv = ((const int*)m)[idx] != 0;
      else if (mode == 1) mv = ((const float*)m)[idx] != 0.0f;
      else                mv = ((const unsigned char*)m)[idx] != 0;
      bits |= (u32)mv << c;
    }
    ws0[64 + row * 4 + q] = bits;   // byte offset 256
  }
}

// ---------------- proj: src = W @ ctx, emit fp16 in both layouts ----------------
__global__ __launch_bounds__(256) void proj_kernel(const float* __restrict__ W,
                                                   const float* __restrict__ ctx,
                                                   u16* __restrict__ srcF,
                                                   u16* __restrict__ srcT) {
  __shared__ float sWt[16][33];
  __shared__ float sC[16 * NL];
  const int tid = threadIdx.x;
  const int b = blockIdx.y;
  const int i0 = blockIdx.x * 32;
  const int tx = tid & 31;   // l quad
  const int ty = tid >> 5;   // i group of 4
  float acc[4][4] = {};
  const float* ctxb = ctx + (size_t)b * CDF * NL;
  for (int c0 = 0; c0 < CDF; c0 += 16) {
    if (tid < 128) {
      int i = tid >> 2, cq = tid & 3;
      float4 w4 = *(const float4*)(W + (size_t)(i0 + i) * CDF + c0 + cq * 4);
      sWt[cq * 4 + 0][i] = w4.x; sWt[cq * 4 + 1][i] = w4.y;
      sWt[cq * 4 + 2][i] = w4.z; sWt[cq * 4 + 3][i] = w4.w;
    }
#pragma unroll
    for (int k = 0; k < 2; ++k) {
      int idx = tid + k * 256;
      int r = idx >> 5, c4 = idx & 31;
      *(float4*)(sC + r * NL + c4 * 4) =
          *(const float4*)(ctxb + (size_t)(c0 + r) * NL + c4 * 4);
    }
    __syncthreads();
#pragma unroll
    for (int cc = 0; cc < 16; ++cc) {
      float4 c4 = *(const float4*)(sC + cc * NL + tx * 4);
#pragma unroll
      for (int ii = 0; ii < 4; ++ii) {
        float w = sWt[cc][ty * 4 + ii];
        acc[ii][0] = fmaf(w, c4.x, acc[ii][0]);
        acc[ii][1] = fmaf(w, c4.y, acc[ii][1]);
        acc[ii][2] = fmaf(w, c4.z, acc[ii][2]);
        acc[ii][3] = fmaf(w, c4.w, acc[ii][3]);
      }
    }
    __syncthreads();
  }
  u16* sf = srcF + (size_t)b * IDF * NL;
  u16* st = srcT + (size_t)b * NL * IDF;
#pragma unroll
  for (int ii = 0; ii < 4; ++ii) {
    int i = i0 + ty * 4 + ii;
    u32 d0 = pkrtz(acc[ii][0], acc[ii][1]);
    u32 d1 = pkrtz(acc[ii][2], acc[ii][3]);
    *(uint2*)(sf + (size_t)i * NL + tx * 4) = make_uint2(d0, d1);
#pragma unroll
    for (int jl = 0; jl < 4; ++jl)
      st[(size_t)(tx * 4 + jl) * IDF + i] = f2h(acc[ii][jl]);
  }
}

// ---------------- fused attention ----------------
// QK^T computed TRANSPOSED: attnT[l][p] = mfma(A=srcT rows l, B=x cols p).
// No LDS, no barriers in the K-loop; lane m15 owns one p column -> register softmax;
// out1[l][p] written coalesced straight from registers. Single barrier before PV.
__global__ __launch_bounds__(256, 4) void attn_kernel(
    const float* __restrict__ x, const u16* __restrict__ srcF,
    const u16* __restrict__ srcT, const u32* __restrict__ wsm,
    float* __restrict__ out0, float* __restrict__ out1) {
  __shared__ __align__(16) u16 sA[64 * 132];    // attn fp16 [p][l], stride 132

  const int tid = threadIdx.x;
  const int lane = tid & 63;
  const int w = tid >> 6;        // wave 0..3
  const int m15 = lane & 15;
  const int g = lane >> 4;       // 0..3
  const int b = blockIdx.y;
  const int p0 = blockIdx.x * PTILE;
  const int pl = w * 16 + m15;   // local p column owned by this lane: 0..63

  // ---- phase 1: logitsT[128l][64p], K=256 in chunks of 32, zero LDS ----
  f32x4 accq[8];
#pragma unroll
  for (int nt = 0; nt < 8; ++nt) accq[nt] = f32x4{0.f, 0.f, 0.f, 0.f};

  const u16* stb = srcT + (size_t)b * NL * IDF;
  const float* xcol = x + (size_t)b * IDF * HXW + p0 + pl;

#pragma unroll 2
  for (int ic = 0; ic < 8; ++ic) {
    // B-frag: x[k][p] for k = ic*32 + g*8 + j (8 strided dword loads, 64B coalesced)
    float xv[8];
#pragma unroll
    for (int j = 0; j < 8; ++j)
      xv[j] = xcol[(size_t)(ic * 32 + g * 8 + j) * HXW];
    Frag bx;
    bx.u[0] = pkrtz(xv[0], xv[1]); bx.u[1] = pkrtz(xv[2], xv[3]);
    bx.u[2] = pkrtz(xv[4], xv[5]); bx.u[3] = pkrtz(xv[6], xv[7]);
#pragma unroll
    for (int nt = 0; nt < 8; ++nt) {
      Frag af;   // A[l][k]: contiguous from L2-resident srcT
      af.u4 = *(const uint4*)(stb + (size_t)(nt * 16 + m15) * IDF + ic * 32 + g * 8);
      accq[nt] = __builtin_amdgcn_mfma_f32_16x16x32_f16(af.v, bx.v, accq[nt], 0, 0, 0);
    }
  }

  // ---- phase 2: masked softmax — each lane owns column p = pl, rows l = nt*16+g*4+r ----
  const int rm = pl & 31;        // mask row = p % 32  (p0 is a multiple of 64)
  uint4 mr = *(const uint4*)(wsm + rm * 4);
  u32 mw[4] = {mr.x, mr.y, mr.z, mr.w};
  float mx = -3.0e38f;
#pragma unroll
  for (int nt = 0; nt < 8; ++nt) {
    u32 bits = mw[nt >> 1] >> ((nt & 1) * 16);
#pragma unroll
    for (int r = 0; r < 4; ++r) {
      if ((bits >> (g * 4 + r)) & 1u) accq[nt][r] = -3.0e38f;
      mx = fmaxf(mx, accq[nt][r]);
    }
  }
  mx = fmaxf(mx, __shfl_xor(mx, 16));
  mx = fmaxf(mx, __shfl_xor(mx, 32));
  float s = 0.f;
#pragma unroll
  for (int nt = 0; nt < 8; ++nt)
#pragma unroll
    for (int r = 0; r < 4; ++r) {
      float e = __expf(accq[nt][r] - mx);
      accq[nt][r] = e;
      s += e;
    }
  s += __shfl_xor(s, 16);
  s += __shfl_xor(s, 32);
  const float inv = 1.0f / s;

  // ---- phase 3: out1[l][p] straight from regs (coalesced), sA fp16 for PV ----
  float* o1 = out1 + (size_t)b * NL * HXW + p0 + pl;
  u32* sAd = (u32*)sA;
#pragma unroll
  for (int nt = 0; nt < 8; ++nt) {
#pragma unroll
    for (int r = 0; r < 4; ++r) {
      float v = accq[nt][r] * inv;
      accq[nt][r] = v;
      o1[(size_t)(nt * 16 + g * 4 + r) * HXW] = v;
    }
    sAd[pl * 66 + nt * 8 + g * 2 + 0] = pkrtz(accq[nt][0], accq[nt][1]);
    sAd[pl * 66 + nt * 8 + g * 2 + 1] = pkrtz(accq[nt][2], accq[nt][3]);
  }
  __syncthreads();

  // ---- phase 4: PV — out0[i][p] = mfma(srcF rows i, attn rows p) ----
  f32x4 accp[4][4];
#pragma unroll
  for (int mt = 0; mt < 4; ++mt)
#pragma unroll
    for (int nt2 = 0; nt2 < 4; ++nt2) accp[mt][nt2] = f32x4{0.f, 0.f, 0.f, 0.f};

  const u16* sfb = srcF + (size_t)b * IDF * NL;
#pragma unroll
  for (int ks = 0; ks < 4; ++ks) {
    Frag af[4], bf[4];
#pragma unroll
    for (int mt = 0; mt < 4; ++mt)
      af[mt].u4 = *(const uint4*)(sfb + (size_t)(w * 64 + mt * 16 + m15) * NL + ks * 32 + g * 8);
#pragma unroll
    for (int nt2 = 0; nt2 < 4; ++nt2) {
      int di = (nt2 * 16 + m15) * 66 + ks * 16 + g * 4;
      bf[nt2].u2[0] = *(const uint2*)(sAd + di);
      bf[nt2].u2[1] = *(const uint2*)(sAd + di + 2);
    }
#pragma unroll
    for (int mt = 0; mt < 4; ++mt)
#pragma unroll
      for (int nt2 = 0; nt2 < 4; ++nt2)
        accp[mt][nt2] = __builtin_amdgcn_mfma_f32_16x16x32_f16(af[mt].v, bf[nt2].v, accp[mt][nt2], 0, 0, 0);
  }

  float* o0 = out0 + (size_t)b * IDF * HXW + p0;
#pragma unroll
  for (int mt = 0; mt < 4; ++mt)
#pragma unroll
    for (int nt2 = 0; nt2 < 4; ++nt2) {
      int col = nt2 * 16 + m15;
#pragma unroll
      for (int r = 0; r < 4; ++r) {
        int row = w * 64 + mt * 16 + g * 4 + r;
        o0[(size_t)row * HXW + col] = accp[mt][nt2][r];
      }
    }
}

extern "C" void kernel_launch(void* const* d_in, const int* in_sizes, int n_in,
                              void* d_out, int out_size, void* d_ws, size_t ws_size,
                              hipStream_t stream) {
  const float* x   = (const float*)d_in[0];
  const float* ctx = (const float*)d_in[1];
  const float* W   = (const float*)d_in[2];
  const void*  msk = d_in[3];
  float* out0 = (float*)d_out;                       // [32][256][64][64]
  float* out1 = out0 + (size_t)NB * IDF * HXW;       // [32][128][64][64]
  u32* ws0 = (u32*)d_ws;
  u16* srcF = (u16*)((char*)d_ws + 1024);            // [32][256][128] f16
  u16* srcT = (u16*)((char*)d_ws + 1024 + 2097152);  // [32][128][256] f16

  prep_kernel<<<1, 256, 0, stream>>>((const u32*)msk, ws0);
  proj_kernel<<<dim3(8, NB), 256, 0, stream>>>(W, ctx, srcF, srcT);
  attn_kernel<<<dim3(HXW / PTILE, NB), 256, 0, stream>>>(x, srcF, srcT, ws0 + 64, out0, out1);
}

// Round 5
// 168.116 us; speedup vs baseline: 1.0579x; 1.0579x over previous
//
#include <hip/hip_runtime.h>
#include <cstdint>

#define IDF 256
#define CDF 256
#define NL  128
#define HXW 4096
#define NB  32
#define PTILE 64

typedef _Float16 f16x8 __attribute__((ext_vector_type(8)));
typedef __fp16 fp16x2 __attribute__((ext_vector_type(2)));
typedef float f32x4 __attribute__((ext_vector_type(4)));
typedef unsigned short u16;
typedef unsigned int u32;

union Frag { f16x8 v; u32 u[4]; uint2 u2[2]; uint4 u4; };

__device__ __forceinline__ u16 f2h(float f) { union { _Float16 h; u16 s; } c; c.h = (_Float16)f; return c.s; }
__device__ __forceinline__ u32 pkrtz(float a, float b) {
  union { fp16x2 v; u32 u; } c;
  c.v = __builtin_amdgcn_cvt_pkrtz(a, b);
  return c.u;
}

// ws layout (bytes): [0..3] mode flag; [256..767] packed mask bits (32 rows x 4 u32);
// [1024 ..] srcF f16 [b][i][l] (2 MB); [+2MB ..] srcT f16 [b][l][i] (2 MB).

// ---------------- proj (+ fused mask prep in block (0,0)) ----------------
__global__ __launch_bounds__(256) void proj_kernel(const float* __restrict__ W,
                                                   const float* __restrict__ ctx,
                                                   u16* __restrict__ srcF,
                                                   u16* __restrict__ srcT,
                                                   const u32* __restrict__ msk,
                                                   u32* __restrict__ ws0) {
  const int tid = threadIdx.x;
  // ---- mask prep (block (0,0) only; block-uniform barriers) ----
  if (blockIdx.x == 0 && blockIdx.y == 0) {
    __shared__ int bi_s, bf_s, mode_s;
    if (tid == 0) { bi_s = 0; bf_s = 0; }
    __syncthreads();
    int bi = 0, bfl = 0;
    for (int k = 0; k < 4; ++k) {
      u32 v = msk[tid * 4 + k];   // first 4KB: valid subset for i32/f32/u8
      if (v > 1u) bi = 1;         // int32 0/1 never exceeds 1
      float f = __uint_as_float(v);
      if (!(f == 0.0f || f == 1.0f)) bfl = 1;
    }
    if (bi) atomicOr(&bi_s, 1);
    if (bfl) atomicOr(&bf_s, 1);
    __syncthreads();
    if (tid == 0) { mode_s = (bi_s == 0) ? 0 : ((bf_s == 0) ? 1 : 2); ws0[0] = (u32)mode_s; }
    __syncthreads();
    const int mode = mode_s;
    if (tid < 128) {
      int row = tid >> 2, q = tid & 3;
      u32 bits = 0;
      for (int c = 0; c < 32; ++c) {
        int idx = row * NL + q * 32 + c;
        int mv;
        if (mode == 0)      mv = ((const int*)msk)[idx] != 0;
        else if (mode == 1) mv = ((const float*)msk)[idx] != 0.0f;
        else                mv = ((const unsigned char*)msk)[idx] != 0;
        bits |= (u32)mv << c;
      }
      ws0[64 + row * 4 + q] = bits;   // byte offset 256
    }
  }

  // ---- proj body ----
  __shared__ float sWt[16][33];
  __shared__ float sC[16 * NL];
  const int b = blockIdx.y;
  const int i0 = blockIdx.x * 32;
  const int tx = tid & 31;   // l quad
  const int ty = tid >> 5;   // i group of 4
  float acc[4][4] = {};
  const float* ctxb = ctx + (size_t)b * CDF * NL;
  for (int c0 = 0; c0 < CDF; c0 += 16) {
    if (tid < 128) {
      int i = tid >> 2, cq = tid & 3;
      float4 w4 = *(const float4*)(W + (size_t)(i0 + i) * CDF + c0 + cq * 4);
      sWt[cq * 4 + 0][i] = w4.x; sWt[cq * 4 + 1][i] = w4.y;
      sWt[cq * 4 + 2][i] = w4.z; sWt[cq * 4 + 3][i] = w4.w;
    }
#pragma unroll
    for (int k = 0; k < 2; ++k) {
      int idx = tid + k * 256;
      int r = idx >> 5, c4 = idx & 31;
      *(float4*)(sC + r * NL + c4 * 4) =
          *(const float4*)(ctxb + (size_t)(c0 + r) * NL + c4 * 4);
    }
    __syncthreads();
#pragma unroll
    for (int cc = 0; cc < 16; ++cc) {
      float4 c4 = *(const float4*)(sC + cc * NL + tx * 4);
#pragma unroll
      for (int ii = 0; ii < 4; ++ii) {
        float w = sWt[cc][ty * 4 + ii];
        acc[ii][0] = fmaf(w, c4.x, acc[ii][0]);
        acc[ii][1] = fmaf(w, c4.y, acc[ii][1]);
        acc[ii][2] = fmaf(w, c4.z, acc[ii][2]);
        acc[ii][3] = fmaf(w, c4.w, acc[ii][3]);
      }
    }
    __syncthreads();
  }
  u16* sf = srcF + (size_t)b * IDF * NL;
  u16* st = srcT + (size_t)b * NL * IDF;
#pragma unroll
  for (int ii = 0; ii < 4; ++ii) {
    int i = i0 + ty * 4 + ii;
    u32 d0 = pkrtz(acc[ii][0], acc[ii][1]);
    u32 d1 = pkrtz(acc[ii][2], acc[ii][3]);
    *(uint2*)(sf + (size_t)i * NL + tx * 4) = make_uint2(d0, d1);
#pragma unroll
    for (int jl = 0; jl < 4; ++jl)
      st[(size_t)(tx * 4 + jl) * IDF + i] = f2h(acc[ii][jl]);
  }
}

// ---------------- fused attention ----------------
// attnT[l][p] = mfma(A=srcT rows l, B=x cols p). x is fed via coalesced float4
// loads + wave-private LDS transpose (parity-dbuf, stride-17 pad, no barriers).
// Lane owns one p column -> register softmax; out1 written coalesced from regs.
// Single block barrier before PV.
__global__ __launch_bounds__(256, 4) void attn_kernel(
    const float* __restrict__ x, const u16* __restrict__ srcF,
    const u16* __restrict__ srcT, const u32* __restrict__ wsm,
    float* __restrict__ out0, float* __restrict__ out1) {
  __shared__ __align__(16) u16 sA[64 * 132];      // attn fp16 [p][l], stride 132
  __shared__ float sX[4 * 2 * 544];               // per-wave [2 par][32 k][17 p] f32

  const int tid = threadIdx.x;
  const int lane = tid & 63;
  const int w = tid >> 6;        // wave 0..3
  const int m15 = lane & 15;
  const int g = lane >> 4;       // 0..3
  const int lq = lane >> 2;      // 0..15: k offset within chunk-half
  const int lp4 = (lane & 3) * 4;  // p quad within wave's 16-p panel
  const int b = blockIdx.y;
  const int p0 = blockIdx.x * PTILE;
  const int pl = w * 16 + m15;   // p column owned by this lane: 0..63

  // ---- phase 1: logitsT[128l][64p], K=256 in chunks of 32 ----
  f32x4 accq[8];
#pragma unroll
  for (int nt = 0; nt < 8; ++nt) accq[nt] = f32x4{0.f, 0.f, 0.f, 0.f};

  const u16* stb = srcT + (size_t)b * NL * IDF;
  const float* xw = x + (size_t)b * IDF * HXW + p0 + w * 16;
  float* sxw_base = sX + w * 1088;

  float4 xc0, xc1, xn0, xn1;
  xc0 = *(const float4*)(xw + (size_t)lq * HXW + lp4);
  xc1 = *(const float4*)(xw + (size_t)(16 + lq) * HXW + lp4);

#pragma unroll
  for (int ic = 0; ic < 8; ++ic) {
    if (ic < 7) {   // prefetch next chunk (compile-time branch)
      xn0 = *(const float4*)(xw + (size_t)((ic + 1) * 32 + lq) * HXW + lp4);
      xn1 = *(const float4*)(xw + (size_t)((ic + 1) * 32 + 16 + lq) * HXW + lp4);
    }
    float* sxw = sxw_base + (ic & 1) * 544;
    const int d0 = lq * 17 + lp4;
    sxw[d0 + 0] = xc0.x; sxw[d0 + 1] = xc0.y; sxw[d0 + 2] = xc0.z; sxw[d0 + 3] = xc0.w;
    sxw[d0 + 272] = xc1.x; sxw[d0 + 273] = xc1.y; sxw[d0 + 274] = xc1.z; sxw[d0 + 275] = xc1.w;
    // frag read: lane m15 -> p, k = g*8+j (2-way banks: free)
    float xv[8];
#pragma unroll
    for (int j = 0; j < 8; ++j) xv[j] = sxw[(g * 8 + j) * 17 + m15];
    Frag bx;
    bx.u[0] = pkrtz(xv[0], xv[1]); bx.u[1] = pkrtz(xv[2], xv[3]);
    bx.u[2] = pkrtz(xv[4], xv[5]); bx.u[3] = pkrtz(xv[6], xv[7]);
    Frag bf[8];
#pragma unroll
    for (int nt = 0; nt < 8; ++nt)
      bf[nt].u4 = *(const uint4*)(stb + (size_t)(nt * 16 + m15) * IDF + ic * 32 + g * 8);
#pragma unroll
    for (int nt = 0; nt < 8; ++nt)
      accq[nt] = __builtin_amdgcn_mfma_f32_16x16x32_f16(bf[nt].v, bx.v, accq[nt], 0, 0, 0);
    xc0 = xn0; xc1 = xn1;
  }

  // ---- phase 2: masked softmax — lane owns column p = pl, rows l = nt*16+g*4+r ----
  const int rm = pl & 31;        // mask row = p % 32  (p0 is a multiple of 64)
  uint4 mr = *(const uint4*)(wsm + rm * 4);
  u32 mw[4] = {mr.x, mr.y, mr.z, mr.w};
  float mx = -3.0e38f;
#pragma unroll
  for (int nt = 0; nt < 8; ++nt) {
    u32 bits = mw[nt >> 1] >> ((nt & 1) * 16);
#pragma unroll
    for (int r = 0; r < 4; ++r) {
      if ((bits >> (g * 4 + r)) & 1u) accq[nt][r] = -3.0e38f;
      mx = fmaxf(mx, accq[nt][r]);
    }
  }
  mx = fmaxf(mx, __shfl_xor(mx, 16));
  mx = fmaxf(mx, __shfl_xor(mx, 32));
  float s = 0.f;
#pragma unroll
  for (int nt = 0; nt < 8; ++nt)
#pragma unroll
    for (int r = 0; r < 4; ++r) {
      float e = __expf(accq[nt][r] - mx);
      accq[nt][r] = e;
      s += e;
    }
  s += __shfl_xor(s, 16);
  s += __shfl_xor(s, 32);
  const float inv = 1.0f / s;

  // ---- phase 3: out1[l][p] straight from regs (coalesced), sA fp16 for PV ----
  float* o1 = out1 + (size_t)b * NL * HXW + p0 + pl;
  u32* sAd = (u32*)sA;
#pragma unroll
  for (int nt = 0; nt < 8; ++nt) {
#pragma unroll
    for (int r = 0; r < 4; ++r) {
      float v = accq[nt][r] * inv;
      accq[nt][r] = v;
      o1[(size_t)(nt * 16 + g * 4 + r) * HXW] = v;
    }
    sAd[pl * 66 + nt * 8 + g * 2 + 0] = pkrtz(accq[nt][0], accq[nt][1]);
    sAd[pl * 66 + nt * 8 + g * 2 + 1] = pkrtz(accq[nt][2], accq[nt][3]);
  }
  __syncthreads();

  // ---- phase 4: PV — out0[i][p] = mfma(srcF rows i, attn rows p) ----
  f32x4 accp[4][4];
#pragma unroll
  for (int mt = 0; mt < 4; ++mt)
#pragma unroll
    for (int nt2 = 0; nt2 < 4; ++nt2) accp[mt][nt2] = f32x4{0.f, 0.f, 0.f, 0.f};

  const u16* sfb = srcF + (size_t)b * IDF * NL;
#pragma unroll
  for (int ks = 0; ks < 4; ++ks) {
    Frag af[4], bf[4];
#pragma unroll
    for (int mt = 0; mt < 4; ++mt)
      af[mt].u4 = *(const uint4*)(sfb + (size_t)(w * 64 + mt * 16 + m15) * NL + ks * 32 + g * 8);
#pragma unroll
    for (int nt2 = 0; nt2 < 4; ++nt2) {
      int di = (nt2 * 16 + m15) * 66 + ks * 16 + g * 4;
      bf[nt2].u2[0] = *(const uint2*)(sAd + di);
      bf[nt2].u2[1] = *(const uint2*)(sAd + di + 2);
    }
#pragma unroll
    for (int mt = 0; mt < 4; ++mt)
#pragma unroll
      for (int nt2 = 0; nt2 < 4; ++nt2)
        accp[mt][nt2] = __builtin_amdgcn_mfma_f32_16x16x32_f16(af[mt].v, bf[nt2].v, accp[mt][nt2], 0, 0, 0);
  }

  float* o0 = out0 + (size_t)b * IDF * HXW + p0;
#pragma unroll
  for (int mt = 0; mt < 4; ++mt)
#pragma unroll
    for (int nt2 = 0; nt2 < 4; ++nt2) {
      int col = nt2 * 16 + m15;
#pragma unroll
      for (int r = 0; r < 4; ++r) {
        int row = w * 64 + mt * 16 + g * 4 + r;
        o0[(size_t)row * HXW + col] = accp[mt][nt2][r];
      }
    }
}

extern "C" void kernel_launch(void* const* d_in, const int* in_sizes, int n_in,
                              void* d_out, int out_size, void* d_ws, size_t ws_size,
                              hipStream_t stream) {
  const float* x   = (const float*)d_in[0];
  const float* ctx = (const float*)d_in[1];
  const float* W   = (const float*)d_in[2];
  const void*  msk = d_in[3];
  float* out0 = (float*)d_out;                       // [32][256][64][64]
  float* out1 = out0 + (size_t)NB * IDF * HXW;       // [32][128][64][64]
  u32* ws0 = (u32*)d_ws;
  u16* srcF = (u16*)((char*)d_ws + 1024);            // [32][256][128] f16
  u16* srcT = (u16*)((char*)d_ws + 1024 + 2097152);  // [32][128][256] f16

  proj_kernel<<<dim3(8, NB), 256, 0, stream>>>(W, ctx, srcF, srcT, (const u32*)msk, ws0);
  attn_kernel<<<dim3(HXW / PTILE, NB), 256, 0, stream>>>(x, srcF, srcT, ws0 + 64, out0, out1);
}

// Round 6
// 151.229 us; speedup vs baseline: 1.1761x; 1.1117x over previous
//
#include <hip/hip_runtime.h>
#include <cstdint>

#define IDF 256
#define CDF 256
#define NL  128
#define HXW 4096
#define NB  32
#define PTILE 64

typedef _Float16 f16x8 __attribute__((ext_vector_type(8)));
typedef __fp16 fp16x2 __attribute__((ext_vector_type(2)));
typedef float f32x4 __attribute__((ext_vector_type(4)));
typedef unsigned short u16;
typedef unsigned int u32;

union Frag { f16x8 v; u32 u[4]; uint2 u2[2]; uint4 u4; };

__device__ __forceinline__ u16 f2h(float f) { union { _Float16 h; u16 s; } c; c.h = (_Float16)f; return c.s; }
__device__ __forceinline__ u32 pkrtz(float a, float b) {
  union { fp16x2 v; u32 u; } c;
  c.v = __builtin_amdgcn_cvt_pkrtz(a, b);
  return c.u;
}

// ws layout (bytes): [0..3] mode flag; [256..767] packed mask bits (32 rows x 4 u32);
// [1024 ..] srcF f16 [b][i][l] (2 MB); [+2MB ..] srcT f16 [b][l][i] (2 MB).

// ---------------- proj (+ fused mask prep in block (0,0)) ----------------
__global__ __launch_bounds__(256) void proj_kernel(const float* __restrict__ W,
                                                   const float* __restrict__ ctx,
                                                   u16* __restrict__ srcF,
                                                   u16* __restrict__ srcT,
                                                   const u32* __restrict__ msk,
                                                   u32* __restrict__ ws0) {
  const int tid = threadIdx.x;
  // ---- mask prep (block (0,0) only; block-uniform barriers) ----
  if (blockIdx.x == 0 && blockIdx.y == 0) {
    __shared__ int bi_s, bf_s, mode_s;
    if (tid == 0) { bi_s = 0; bf_s = 0; }
    __syncthreads();
    int bi = 0, bfl = 0;
    for (int k = 0; k < 4; ++k) {
      u32 v = msk[tid * 4 + k];   // first 4KB: valid subset for i32/f32/u8
      if (v > 1u) bi = 1;         // int32 0/1 never exceeds 1
      float f = __uint_as_float(v);
      if (!(f == 0.0f || f == 1.0f)) bfl = 1;
    }
    if (bi) atomicOr(&bi_s, 1);
    if (bfl) atomicOr(&bf_s, 1);
    __syncthreads();
    if (tid == 0) { mode_s = (bi_s == 0) ? 0 : ((bf_s == 0) ? 1 : 2); ws0[0] = (u32)mode_s; }
    __syncthreads();
    const int mode = mode_s;
    if (tid < 128) {
      int row = tid >> 2, q = tid & 3;
      u32 bits = 0;
      for (int c = 0; c < 32; ++c) {
        int idx = row * NL + q * 32 + c;
        int mv;
        if (mode == 0)      mv = ((const int*)msk)[idx] != 0;
        else if (mode == 1) mv = ((const float*)msk)[idx] != 0.0f;
        else                mv = ((const unsigned char*)msk)[idx] != 0;
        bits |= (u32)mv << c;
      }
      ws0[64 + row * 4 + q] = bits;   // byte offset 256
    }
  }

  // ---- proj body ----
  __shared__ float sWt[16][33];
  __shared__ float sC[16 * NL];
  const int b = blockIdx.y;
  const int i0 = blockIdx.x * 32;
  const int tx = tid & 31;   // l quad
  const int ty = tid >> 5;   // i group of 4
  float acc[4][4] = {};
  const float* ctxb = ctx + (size_t)b * CDF * NL;
  for (int c0 = 0; c0 < CDF; c0 += 16) {
    if (tid < 128) {
      int i = tid >> 2, cq = tid & 3;
      float4 w4 = *(const float4*)(W + (size_t)(i0 + i) * CDF + c0 + cq * 4);
      sWt[cq * 4 + 0][i] = w4.x; sWt[cq * 4 + 1][i] = w4.y;
      sWt[cq * 4 + 2][i] = w4.z; sWt[cq * 4 + 3][i] = w4.w;
    }
#pragma unroll
    for (int k = 0; k < 2; ++k) {
      int idx = tid + k * 256;
      int r = idx >> 5, c4 = idx & 31;
      *(float4*)(sC + r * NL + c4 * 4) =
          *(const float4*)(ctxb + (size_t)(c0 + r) * NL + c4 * 4);
    }
    __syncthreads();
#pragma unroll
    for (int cc = 0; cc < 16; ++cc) {
      float4 c4 = *(const float4*)(sC + cc * NL + tx * 4);
#pragma unroll
      for (int ii = 0; ii < 4; ++ii) {
        float w = sWt[cc][ty * 4 + ii];
        acc[ii][0] = fmaf(w, c4.x, acc[ii][0]);
        acc[ii][1] = fmaf(w, c4.y, acc[ii][1]);
        acc[ii][2] = fmaf(w, c4.z, acc[ii][2]);
        acc[ii][3] = fmaf(w, c4.w, acc[ii][3]);
      }
    }
    __syncthreads();
  }
  u16* sf = srcF + (size_t)b * IDF * NL;
  u16* st = srcT + (size_t)b * NL * IDF;
#pragma unroll
  for (int ii = 0; ii < 4; ++ii) {
    int i = i0 + ty * 4 + ii;
    u32 d0 = pkrtz(acc[ii][0], acc[ii][1]);
    u32 d1 = pkrtz(acc[ii][2], acc[ii][3]);
    *(uint2*)(sf + (size_t)i * NL + tx * 4) = make_uint2(d0, d1);
#pragma unroll
    for (int jl = 0; jl < 4; ++jl)
      st[(size_t)(tx * 4 + jl) * IDF + i] = f2h(acc[ii][jl]);
  }
}

// ---------------- fused attention ----------------
// Phase 0: stage full 256k x 64p x-tile to LDS as f16 k-pairs (16 independent
// float4 loads/thread -> full MLP, one barrier). Phase 1 K-loop: only srcT L2
// loads + conflict-free ds_read_b32 + MFMA (no LDS writes, no barriers).
// Register softmax, direct coalesced out1, sA (aliasing sXT) for PV.
__global__ __launch_bounds__(256, 4) void attn_kernel(
    const float* __restrict__ x, const u16* __restrict__ srcF,
    const u16* __restrict__ srcT, const u32* __restrict__ wsm,
    float* __restrict__ out0, float* __restrict__ out1) {
  __shared__ __align__(16) u32 sBuf[128 * 66];   // 33792 B; sXT then reused as sA

  const int tid = threadIdx.x;
  const int lane = tid & 63;
  const int w = tid >> 6;        // wave 0..3
  const int m15 = lane & 15;
  const int g = lane >> 4;       // 0..3
  const int b = blockIdx.y;
  const int p0 = blockIdx.x * PTILE;
  const int pl = w * 16 + m15;   // p column owned by this lane: 0..63

  // ---- phase 0: stage x tile -> sXT[kp][p] (u32 = f16 pair (2kp, 2kp+1)) ----
  {
    const float* xb = x + (size_t)b * IDF * HXW + p0;
    const int t16 = tid >> 4;        // 0..15
    const int p4 = (tid & 15) * 4;   // p quad
    float4 lo[8], hi[8];
#pragma unroll
    for (int it = 0; it < 8; ++it) {
      const float* rp = xb + (size_t)(it * 32 + t16 * 2) * HXW + p4;
      lo[it] = *(const float4*)rp;
      hi[it] = *(const float4*)(rp + HXW);
    }
#pragma unroll
    for (int it = 0; it < 8; ++it) {
      int base = (it * 16 + t16) * 66 + p4;
      u32 r0 = pkrtz(lo[it].x, hi[it].x);
      u32 r1 = pkrtz(lo[it].y, hi[it].y);
      u32 r2 = pkrtz(lo[it].z, hi[it].z);
      u32 r3 = pkrtz(lo[it].w, hi[it].w);
      *(uint2*)(sBuf + base + 0) = make_uint2(r0, r1);
      *(uint2*)(sBuf + base + 2) = make_uint2(r2, r3);
    }
  }
  __syncthreads();

  // ---- phase 1: logitsT[128l][64p], K=256 in chunks of 32 ----
  f32x4 accq[8];
#pragma unroll
  for (int nt = 0; nt < 8; ++nt) accq[nt] = f32x4{0.f, 0.f, 0.f, 0.f};

  const u16* stb = srcT + (size_t)b * NL * IDF;
#pragma unroll
  for (int ic = 0; ic < 8; ++ic) {
    Frag bf[8];   // srcT: sole vmem stream (L2), issued first
#pragma unroll
    for (int nt = 0; nt < 8; ++nt)
      bf[nt].u4 = *(const uint4*)(stb + (size_t)(nt * 16 + m15) * IDF + ic * 32 + g * 8);
    Frag bx;      // x frag from LDS: rows kp = ic*16+g*4+jj, col pl (2-way banks: free)
#pragma unroll
    for (int jj = 0; jj < 4; ++jj)
      bx.u[jj] = sBuf[(ic * 16 + g * 4 + jj) * 66 + pl];
#pragma unroll
    for (int nt = 0; nt < 8; ++nt)
      accq[nt] = __builtin_amdgcn_mfma_f32_16x16x32_f16(bf[nt].v, bx.v, accq[nt], 0, 0, 0);
  }

  // ---- phase 2: masked softmax — lane owns column p = pl, rows l = nt*16+g*4+r ----
  const int rm = pl & 31;        // mask row = p % 32  (p0 is a multiple of 64)
  uint4 mr = *(const uint4*)(wsm + rm * 4);
  u32 mw[4] = {mr.x, mr.y, mr.z, mr.w};
  float mx = -3.0e38f;
#pragma unroll
  for (int nt = 0; nt < 8; ++nt) {
    u32 bits = mw[nt >> 1] >> ((nt & 1) * 16);
#pragma unroll
    for (int r = 0; r < 4; ++r) {
      if ((bits >> (g * 4 + r)) & 1u) accq[nt][r] = -3.0e38f;
      mx = fmaxf(mx, accq[nt][r]);
    }
  }
  mx = fmaxf(mx, __shfl_xor(mx, 16));
  mx = fmaxf(mx, __shfl_xor(mx, 32));
  float s = 0.f;
#pragma unroll
  for (int nt = 0; nt < 8; ++nt)
#pragma unroll
    for (int r = 0; r < 4; ++r) {
      float e = __expf(accq[nt][r] - mx);
      accq[nt][r] = e;
      s += e;
    }
  s += __shfl_xor(s, 16);
  s += __shfl_xor(s, 32);
  const float inv = 1.0f / s;

  // ---- phase 3: out1[l][p] straight from regs (coalesced) ----
  float* o1 = out1 + (size_t)b * NL * HXW + p0 + pl;
#pragma unroll
  for (int nt = 0; nt < 8; ++nt)
#pragma unroll
    for (int r = 0; r < 4; ++r) {
      float v = accq[nt][r] * inv;
      accq[nt][r] = v;
      o1[(size_t)(nt * 16 + g * 4 + r) * HXW] = v;
    }
  __syncthreads();   // all waves done reading sXT; sBuf becomes sA
#pragma unroll
  for (int nt = 0; nt < 8; ++nt) {
    sBuf[pl * 66 + nt * 8 + g * 2 + 0] = pkrtz(accq[nt][0], accq[nt][1]);
    sBuf[pl * 66 + nt * 8 + g * 2 + 1] = pkrtz(accq[nt][2], accq[nt][3]);
  }
  __syncthreads();

  // ---- phase 4: PV — out0[i][p] = mfma(srcF rows i, attn rows p) ----
  f32x4 accp[4][4];
#pragma unroll
  for (int mt = 0; mt < 4; ++mt)
#pragma unroll
    for (int nt2 = 0; nt2 < 4; ++nt2) accp[mt][nt2] = f32x4{0.f, 0.f, 0.f, 0.f};

  const u16* sfb = srcF + (size_t)b * IDF * NL;
#pragma unroll
  for (int ks = 0; ks < 4; ++ks) {
    Frag af[4], bf[4];
#pragma unroll
    for (int mt = 0; mt < 4; ++mt)
      af[mt].u4 = *(const uint4*)(sfb + (size_t)(w * 64 + mt * 16 + m15) * NL + ks * 32 + g * 8);
#pragma unroll
    for (int nt2 = 0; nt2 < 4; ++nt2) {
      int di = (nt2 * 16 + m15) * 66 + ks * 16 + g * 4;
      bf[nt2].u2[0] = *(const uint2*)(sBuf + di);
      bf[nt2].u2[1] = *(const uint2*)(sBuf + di + 2);
    }
#pragma unroll
    for (int mt = 0; mt < 4; ++mt)
#pragma unroll
      for (int nt2 = 0; nt2 < 4; ++nt2)
        accp[mt][nt2] = __builtin_amdgcn_mfma_f32_16x16x32_f16(af[mt].v, bf[nt2].v, accp[mt][nt2], 0, 0, 0);
  }

  float* o0 = out0 + (size_t)b * IDF * HXW + p0;
#pragma unroll
  for (int mt = 0; mt < 4; ++mt)
#pragma unroll
    for (int nt2 = 0; nt2 < 4; ++nt2) {
      int col = nt2 * 16 + m15;
#pragma unroll
      for (int r = 0; r < 4; ++r) {
        int row = w * 64 + mt * 16 + g * 4 + r;
        o0[(size_t)row * HXW + col] = accp[mt][nt2][r];
      }
    }
}

extern "C" void kernel_launch(void* const* d_in, const int* in_sizes, int n_in,
                              void* d_out, int out_size, void* d_ws, size_t ws_size,
                              hipStream_t stream) {
  const float* x   = (const float*)d_in[0];
  const float* ctx = (const float*)d_in[1];
  const float* W   = (const float*)d_in[2];
  const void*  msk = d_in[3];
  float* out0 = (float*)d_out;                       // [32][256][64][64]
  float* out1 = out0 + (size_t)NB * IDF * HXW;       // [32][128][64][64]
  u32* ws0 = (u32*)d_ws;
  u16* srcF = (u16*)((char*)d_ws + 1024);            // [32][256][128] f16
  u16* srcT = (u16*)((char*)d_ws + 1024 + 2097152);  // [32][128][256] f16

  proj_kernel<<<dim3(8, NB), 256, 0, stream>>>(W, ctx, srcF, srcT, (const u32*)msk, ws0);
  attn_kernel<<<dim3(HXW / PTILE, NB), 256, 0, stream>>>(x, srcF, srcT, ws0 + 64, out0, out1);
}